// Round 16
// baseline (32.984 us; speedup 1.0000x reference)
//
#include <hip/hip_runtime.h>
#include <stdint.h>

#define NE 64        // real experts (ids in [0,64))
#define E  65        // num_experts + 1 (expert 64 always empty)
#define BLK 128      // block_size
#define CHB 64       // rows per scan chunk (both paths)

// ---- fast-path geometry: 8192 tokens per 512-thread block, 3 launches ----
#define T1 512
#define W1 8
#define TPB1 8192
#define NB1 1024
#define NC1 16

// ---- fallback (R9, proven) geometry ----
#define THREADS 256
#define WPB 4
#define TPB 4096

// ================= fast path =================

// k_rank: per-wave stable ranks via ds_add_rtn (lane-ordered, proven R9) ->
// packed u16 pairs + per-wave counts (u16) + block counts. topk read ONCE here.
__global__ void __launch_bounds__(T1) k_rank(const int* __restrict__ topk,
                                             uint32_t* __restrict__ packed,
                                             unsigned short* __restrict__ wcnt16,
                                             int* __restrict__ bcnt) {
    __shared__ int lrun[W1][NE];
    const int tid = threadIdx.x, w = tid >> 6, lane = tid & 63;
    const int b = blockIdx.x;
    lrun[w][lane] = 0;              // wave-private row: same-wave DS order, no barrier
    const int wstart = b * TPB1 + w * 1024;
    uint32_t pk[8];
#pragma unroll
    for (int it = 0; it < 16; ++it) {
        int e = topk[wstart + it * 64 + lane] & 63;
        int r = atomicAdd(&lrun[w][e], 1);           // rank, ascending (it,lane) order
        uint32_t p = ((uint32_t)e << 10) | (uint32_t)r;   // r < 1024
        if (it & 1) pk[it >> 1] |= p; else pk[it >> 1] = p << 16;
    }
#pragma unroll
    for (int q = 0; q < 8; ++q)
        packed[(size_t)b * 4096 + w * 512 + q * 64 + lane] = pk[q];
    wcnt16[b * (W1 * NE) + w * NE + lane] = (unsigned short)lrun[w][lane]; // <= 1024
    __syncthreads();
    if (tid < NE) {
        int s = 0;
#pragma unroll
        for (int w2 = 0; w2 < W1; ++w2) s += lrun[w2][tid];
        bcnt[b * NE + tid] = s;
    }
}

// k_scan1: in-chunk exclusive prefix of bcnt over CHB rows; chunk totals
__global__ void k_scan1(int* __restrict__ bcnt, int* __restrict__ ctot) {
    __shared__ int tile[CHB * NE];
    const int c = blockIdx.x, tid = threadIdx.x;
    for (int i = tid; i < CHB * NE; i += THREADS) tile[i] = bcnt[c * CHB * NE + i];
    __syncthreads();
    if (tid < NE) {
        int acc = 0;
#pragma unroll 8
        for (int j = 0; j < CHB; ++j) { int o = tile[j * NE + tid]; tile[j * NE + tid] = acc; acc += o; }
        ctot[c * NE + tid] = acc;
    }
    __syncthreads();
    for (int i = tid; i < CHB * NE; i += THREADS) bcnt[c * CHB * NE + i] = tile[i];
}

// k_sort2: u16 staging + segment-ordered write-out (expert implied by position;
// per-segment loc/len/dbase are uniform scalars -> no per-token shfl in phase D).
__global__ void __launch_bounds__(T1) k_sort2(
        const uint32_t* __restrict__ packed, const unsigned short* __restrict__ wcnt16,
        const int* __restrict__ bpre,   // bcnt after scan1: in-chunk exclusive prefix
        const int* __restrict__ ctot,   // [NC1][NE] chunk totals
        int* __restrict__ sorted, int* __restrict__ eids, int* __restrict__ npp,
        int nb, int M, int T, int epb) {
    __shared__ unsigned short sbuf16[TPB1];   // 16 KB staged local token indices
    __shared__ int cps[E];
    __shared__ int loc_s[NE], len_s[NE], db_s[NE];
    const int tid = threadIdx.x, w = tid >> 6, lane = tid & 63;
    const int b = blockIdx.x, c = b >> 6;

    // global metadata from ctot (replicated; lane owns expert `lane`)
    int ct_pre = 0, cnts = 0;
#pragma unroll
    for (int k = 0; k < NC1; ++k) {
        int v = ctot[k * NE + lane];
        ct_pre += (k < c) ? v : 0;
        cnts += v;
    }
    int padded = (cnts + BLK - 1) & ~(BLK - 1);
    int incl2 = padded;
#pragma unroll
    for (int d = 1; d < 64; d <<= 1) { int t = __shfl_up(incl2, d); if (lane >= d) incl2 += t; }
    int off_lane = incl2 - padded;                   // off_pad[lane]
    int total = __shfl(incl2, 63);                   // num_tokens_post_pad
    if (tid < NE) cps[tid] = incl2;                  // cum_pad[0..63] (wave-0 lanes)
    if (tid == 0) cps[NE] = total;

    uint32_t pk[8];
#pragma unroll
    for (int q = 0; q < 8; ++q)
        pk[q] = packed[(size_t)b * 4096 + w * 512 + q * 64 + lane];

    // block totals + this wave's offset within block (lane owns expert `lane`)
    int btot = 0, woff = 0;
#pragma unroll
    for (int w2 = 0; w2 < W1; ++w2) {
        int v = (int)wcnt16[b * (W1 * NE) + w2 * NE + lane];
        btot += v; woff += (w2 < w) ? v : 0;
    }
    int incl = btot;
#pragma unroll
    for (int d = 1; d < 64; d <<= 1) { int t = __shfl_up(incl, d); if (lane >= d) incl += t; }
    int loc = incl - btot;                            // block-local segment start
    int S = loc + woff;                               // this wave's start
    int dbase = off_lane + ct_pre + bpre[b * NE + lane] - loc;
    if (w == 0) { loc_s[lane] = loc; len_s[lane] = btot; db_s[lane] = dbase; }

    // phase C: place block-local token indices into LDS in sorted order (u16)
    const int wloc = w * 1024;
#pragma unroll
    for (int q = 0; q < 8; ++q) {
        uint32_t pw = pk[q];
        int e0 = (int)(pw >> 26) & 63, r0 = (int)((pw >> 16) & 1023);
        int e1 = (int)((pw >> 10) & 63), r1 = (int)(pw & 1023);
        int p0 = (__shfl(S, e0) + r0) & (TPB1 - 1);   // defensive mask
        int p1 = (__shfl(S, e1) + r1) & (TPB1 - 1);
        sbuf16[p0] = (unsigned short)(wloc + (2 * q) * 64 + lane);
        sbuf16[p1] = (unsigned short)(wloc + (2 * q + 1) * 64 + lane);
    }
    __syncthreads();                                  // publishes sbuf16/cps/tables

    // phase D: segment-ordered write-out; wave w owns experts [w*8, w*8+8)
    const int bstart = b * TPB1;
#pragma unroll
    for (int s0 = 0; s0 < 8; ++s0) {
        int s = w * 8 + s0;
        int l0 = loc_s[s], ln = len_s[s], db = db_s[s];   // uniform scalars
        for (int i = lane; i < ln; i += 64) {
            int pos = l0 + i;
            sorted[db + pos] = bstart + (int)sbuf16[pos];
        }
    }

    // epilogue A: this block's slice of expert_ids
    if (tid < epb) {
        int jb = b * epb + tid;
        if (jb < nb) {
            int bs2 = jb * BLK, r = 0;
            if (bs2 < total) {
                int lo = 0, hi = E;
                while (lo < hi) { int mid = (lo + hi) >> 1; if (cps[mid] <= bs2) lo = mid + 1; else hi = mid; }
                r = lo;
            }
            eids[jb] = r;
        }
    }
    // epilogue B: pad-gap fill (blocks 0..63) and tail fill (blocks 65..81)
    if (b < NE) {
        int cc = __shfl(cnts, b);                     // counts[b]
        int ob = __shfl(off_lane, b);                 // off_pad[b]
        int pe = (cc + BLK - 1) & ~(BLK - 1);
        int len = pe - cc;                            // <= 127
        if (tid < len) sorted[ob + cc + tid] = T;
    } else if (b >= E && b < E + 17) {
        int i = total + (b - E) * T1 + tid;
        if (i < M) sorted[i] = T;                     // tail <= 8255 < 17*512
    }
    if (b == 0 && tid == 0) *npp = total;
}

// ================= fallback path (R9, proven) =================
__global__ void __launch_bounds__(THREADS, 8) k_hist(const int* __restrict__ topk,
                                                     int* __restrict__ bcnt) {
    __shared__ int hist[WPB][NE];
    const int tid = threadIdx.x, w = tid >> 6, lane = tid & 63;
    hist[w][lane] = 0;
    const int base = blockIdx.x * TPB + w * 1024;
#pragma unroll
    for (int it = 0; it < 4; ++it) {
        int4 v = *(const int4*)(topk + base + it * 256 + lane * 4);
        atomicAdd(&hist[w][v.x & 63], 1);
        atomicAdd(&hist[w][v.y & 63], 1);
        atomicAdd(&hist[w][v.z & 63], 1);
        atomicAdd(&hist[w][v.w & 63], 1);
    }
    __syncthreads();
    if (tid < NE)
        bcnt[blockIdx.x * NE + tid] =
            hist[0][tid] + hist[1][tid] + hist[2][tid] + hist[3][tid];
}

__global__ void k_scan2(int* __restrict__ ctot, int* __restrict__ counts,
                        int* __restrict__ off_pad, int* __restrict__ cum_pad,
                        int* __restrict__ npp, int nc) {
    __shared__ int ct[32 * NE];
    const int tid = threadIdx.x;
    for (int i = tid; i < nc * NE; i += THREADS) ct[i] = ctot[i];
    __syncthreads();
    if (tid < NE) {
        int acc = 0;
        for (int c = 0; c < nc; ++c) { int o = ct[c * NE + tid]; ct[c * NE + tid] = acc; acc += o; }
        counts[tid] = acc;
    }
    if (tid == NE) counts[NE] = 0;
    __syncthreads();
    for (int i = tid; i < nc * NE; i += THREADS) ctot[i] = ct[i];
    if (tid == 0) {
        int run = 0;
        for (int e = 0; e < E; ++e) {
            int p = (counts[e] + BLK - 1) & ~(BLK - 1);
            off_pad[e] = run; run += p; cum_pad[e] = run;
        }
        *npp = run;
    }
}

__global__ void __launch_bounds__(THREADS) k_sort(
        const int* __restrict__ topk, const int* __restrict__ bpre,
        const int* __restrict__ ctot, const int* __restrict__ counts,
        const int* __restrict__ off_pad, const int* __restrict__ cum_pad,
        int* __restrict__ sorted, int* __restrict__ eids,
        int nb, int M, int T, int epb) {
    __shared__ int lrun[WPB][NE];
    __shared__ int wt[WPB][NE];
    __shared__ int sbuf[TPB];
    __shared__ int cps[E];
    const int tid = threadIdx.x, w = tid >> 6, lane = tid & 63;
    const int b = blockIdx.x, c = b / CHB;
    if (tid < E) cps[tid] = cum_pad[tid];
    lrun[w][lane] = 0;
    const int wstart = b * TPB + w * 1024;
    int packed[16];
#pragma unroll
    for (int it = 0; it < 16; ++it) {
        int e = topk[wstart + it * 64 + lane] & 63;
        int r = atomicAdd(&lrun[w][e], 1);
        packed[it] = (e << 10) | r;
    }
    wt[w][lane] = lrun[w][lane];
    __syncthreads();
    int woff = 0, btot = 0;
#pragma unroll
    for (int w2 = 0; w2 < WPB; ++w2) { int v = wt[w2][lane]; woff += (w2 < w) ? v : 0; btot += v; }
    int incl = btot;
#pragma unroll
    for (int d = 1; d < 64; d <<= 1) { int t = __shfl_up(incl, d); if (lane >= d) incl += t; }
    int loc = incl - btot;
    int dbase = off_pad[lane] + ctot[c * NE + lane] + bpre[b * NE + lane] - loc;
    int S = loc + woff;
    const int wloc = w * 1024;
#pragma unroll
    for (int it = 0; it < 16; ++it) {
        int e = packed[it] >> 10;
        int r = packed[it] & 1023;
        int pos = (__shfl(S, e) + r) & (TPB - 1);
        sbuf[pos] = (e << 12) | (wloc + it * 64 + lane);
    }
    __syncthreads();
    const int bstart = b * TPB;
#pragma unroll
    for (int k = 0; k < 16; ++k) {
        int j = k * THREADS + tid;
        int p = sbuf[j];
        int e = (p >> 12) & 63;
        int d = __shfl(dbase, e);
        sorted[d + j] = bstart + (p & 0xfff);
    }
    int total = cps[NE - 1];
    if (tid < epb) {
        int j = b * epb + tid;
        if (j < nb) {
            int bs2 = j * BLK, r = 0;
            if (bs2 < total) {
                int lo = 0, hi = E;
                while (lo < hi) { int mid = (lo + hi) >> 1; if (cps[mid] <= bs2) lo = mid + 1; else hi = mid; }
                r = lo;
            }
            eids[j] = r;
        }
    }
    if (b < E) {
        int cc = counts[b];
        int pe = (cc + BLK - 1) & ~(BLK - 1);
        int len = pe - cc;
        if (tid < len) sorted[off_pad[b] + cc + tid] = T;
    } else if (b < E + 33) {
        int i = total + (b - E) * THREADS + tid;
        if (i < M) sorted[i] = T;
    }
}

extern "C" void kernel_launch(void* const* d_in, const int* in_sizes, int n_in,
                              void* d_out, int out_size, void* d_ws, size_t ws_size,
                              hipStream_t stream) {
    const int* topk = (const int*)d_in[0];
    const int T = in_sizes[0];                       // 8388608
    const int M = T + E * (BLK - 1);
    const int nb = M / BLK;

    int* out = (int*)d_out;
    int* sorted = out;
    int* expert_ids = out + M;
    int* npp = out + M + nb;

    // ---- fast path: persisted-ranks, 3 launches ----
    bool fast = (T == NB1 * TPB1);
    size_t need = ((size_t)(T / 2) + (size_t)NB1 * NE + (size_t)NC1 * NE) * sizeof(int)
                + (size_t)NB1 * W1 * NE * sizeof(unsigned short);
    if (need > ws_size) fast = false;

    if (fast) {
        uint32_t* packed = (uint32_t*)d_ws;                          // T/2 u32
        unsigned short* wcnt16 = (unsigned short*)(packed + (size_t)T / 2);  // NB1*8*NE u16
        int* bcnt = (int*)(wcnt16 + (size_t)NB1 * W1 * NE);          // NB1*NE int
        int* ctot = bcnt + (size_t)NB1 * NE;                         // NC1*NE int
        const int epb = (nb + NB1 - 1) / NB1;                        // 65

        k_rank<<<NB1, T1, 0, stream>>>(topk, packed, wcnt16, bcnt);
        k_scan1<<<NC1, THREADS, 0, stream>>>(bcnt, ctot);
        k_sort2<<<NB1, T1, 0, stream>>>(packed, wcnt16, bcnt, ctot,
                                        sorted, expert_ids, npp, nb, M, T, epb);
        return;
    }

    // ---- fallback: proven R9 4-kernel path ----
    const int NB = T / TPB;
    const int NC = NB / CHB;
    const int epb = (nb + NB - 1) / NB;
    int* bcnt    = (int*)d_ws;
    int* ctot    = bcnt + (size_t)NB * NE;
    int* counts  = ctot + (size_t)NC * NE;
    int* off_pad = counts + E;
    int* cum_pad = off_pad + E;

    k_hist<<<NB, THREADS, 0, stream>>>(topk, bcnt);
    k_scan1<<<NC, THREADS, 0, stream>>>(bcnt, ctot);
    k_scan2<<<1, THREADS, 0, stream>>>(ctot, counts, off_pad, cum_pad, npp, NC);
    k_sort<<<NB, THREADS, 0, stream>>>(topk, bcnt, ctot, counts, off_pad, cum_pad,
                                       sorted, expert_ids, nb, M, T, epb);
}

// Round 17
// 31.192 us; speedup vs baseline: 1.0575x; 1.0575x over previous
//
#include <hip/hip_runtime.h>
#include <stdint.h>

#define NE 64        // real experts (ids in [0,64))
#define E  65        // num_experts + 1 (expert 64 always empty)
#define BLK 128      // block_size
#define CHB 64       // rows per scan chunk (both paths)

// ---- fast-path geometry: 8192 tokens per 512-thread block, 3 launches ----
#define T1 512
#define W1 8
#define TPB1 8192
#define NB1 1024
#define NC1 16

// ---- fallback (R9, proven) geometry ----
#define THREADS 256
#define WPB 4
#define TPB 4096

// ================= fast path (R13/R15 structure — best measured) =================

// k_rank: per-wave stable ranks via ds_add_rtn (lane-ordered, proven R9) ->
// packed u16 pairs + per-wave counts (u16) + block counts. topk read ONCE here.
__global__ void __launch_bounds__(T1) k_rank(const int* __restrict__ topk,
                                             uint32_t* __restrict__ packed,
                                             unsigned short* __restrict__ wcnt16,
                                             int* __restrict__ bcnt) {
    __shared__ int lrun[W1][NE];
    const int tid = threadIdx.x, w = tid >> 6, lane = tid & 63;
    const int b = blockIdx.x;
    lrun[w][lane] = 0;              // wave-private row: same-wave DS order, no barrier
    const int wstart = b * TPB1 + w * 1024;
    uint32_t pk[8];
#pragma unroll
    for (int it = 0; it < 16; ++it) {
        int e = topk[wstart + it * 64 + lane] & 63;
        int r = atomicAdd(&lrun[w][e], 1);           // rank, ascending (it,lane) order
        uint32_t p = ((uint32_t)e << 10) | (uint32_t)r;   // r < 1024
        if (it & 1) pk[it >> 1] |= p; else pk[it >> 1] = p << 16;
    }
#pragma unroll
    for (int q = 0; q < 8; ++q)
        packed[(size_t)b * 4096 + w * 512 + q * 64 + lane] = pk[q];
    wcnt16[b * (W1 * NE) + w * NE + lane] = (unsigned short)lrun[w][lane]; // <= 1024
    __syncthreads();
    if (tid < NE) {
        int s = 0;
#pragma unroll
        for (int w2 = 0; w2 < W1; ++w2) s += lrun[w2][tid];
        bcnt[b * NE + tid] = s;
    }
}

// k_scan1: in-chunk exclusive prefix of bcnt over CHB rows; chunk totals
__global__ void k_scan1(int* __restrict__ bcnt, int* __restrict__ ctot) {
    __shared__ int tile[CHB * NE];
    const int c = blockIdx.x, tid = threadIdx.x;
    for (int i = tid; i < CHB * NE; i += THREADS) tile[i] = bcnt[c * CHB * NE + i];
    __syncthreads();
    if (tid < NE) {
        int acc = 0;
#pragma unroll 8
        for (int j = 0; j < CHB; ++j) { int o = tile[j * NE + tid]; tile[j * NE + tid] = acc; acc += o; }
        ctot[c * NE + tid] = acc;
    }
    __syncthreads();
    for (int i = tid; i < CHB * NE; i += THREADS) bcnt[c * CHB * NE + i] = tile[i];
}

// k_sort2: NO atomics, NO topk re-read, NO scan2. Derives global metadata from
// ctot (validated R13 math), reconstructs positions from packed ranks, stages
// 8192 tokens in LDS, segmented-contiguous write-out, fused epilogues.
__global__ void __launch_bounds__(T1) k_sort2(
        const uint32_t* __restrict__ packed, const unsigned short* __restrict__ wcnt16,
        const int* __restrict__ bpre,   // bcnt after scan1: in-chunk exclusive prefix
        const int* __restrict__ ctot,   // [NC1][NE] chunk totals
        int* __restrict__ sorted, int* __restrict__ eids, int* __restrict__ npp,
        int nb, int M, int T, int epb) {
    __shared__ int sbuf[TPB1];       // 32 KB staged sorted tokens
    __shared__ int cps[E];
    const int tid = threadIdx.x, w = tid >> 6, lane = tid & 63;
    const int b = blockIdx.x, c = b >> 6;

    // global metadata from ctot (replicated; lane owns expert `lane`)
    int ct_pre = 0, cnts = 0;
#pragma unroll
    for (int k = 0; k < NC1; ++k) {
        int v = ctot[k * NE + lane];
        ct_pre += (k < c) ? v : 0;
        cnts += v;
    }
    int padded = (cnts + BLK - 1) & ~(BLK - 1);
    int incl2 = padded;
#pragma unroll
    for (int d = 1; d < 64; d <<= 1) { int t = __shfl_up(incl2, d); if (lane >= d) incl2 += t; }
    int off_lane = incl2 - padded;                   // off_pad[lane]
    int total = __shfl(incl2, 63);                   // num_tokens_post_pad
    if (tid < NE) cps[tid] = incl2;                  // cum_pad[0..63] (wave-0 lanes)
    if (tid == 0) cps[NE] = total;

    uint32_t pk[8];
#pragma unroll
    for (int q = 0; q < 8; ++q)
        pk[q] = packed[(size_t)b * 4096 + w * 512 + q * 64 + lane];

    // block totals + this wave's offset within block (lane owns expert `lane`)
    int btot = 0, woff = 0;
#pragma unroll
    for (int w2 = 0; w2 < W1; ++w2) {
        int v = (int)wcnt16[b * (W1 * NE) + w2 * NE + lane];
        btot += v; woff += (w2 < w) ? v : 0;
    }
    int incl = btot;
#pragma unroll
    for (int d = 1; d < 64; d <<= 1) { int t = __shfl_up(incl, d); if (lane >= d) incl += t; }
    int loc = incl - btot;                            // block-local segment start
    int S = loc + woff;                               // this wave's start
    int dbase = off_lane + ct_pre + bpre[b * NE + lane] - loc;

    // phase C: place block-local token ids into LDS in sorted order
    const int wloc = w * 1024;
#pragma unroll
    for (int q = 0; q < 8; ++q) {
        uint32_t pw = pk[q];
        int e0 = (int)(pw >> 26) & 63, r0 = (int)((pw >> 16) & 1023);
        int e1 = (int)((pw >> 10) & 63), r1 = (int)(pw & 1023);
        int p0 = (__shfl(S, e0) + r0) & (TPB1 - 1);
        int p1 = (__shfl(S, e1) + r1) & (TPB1 - 1);
        sbuf[p0] = (e0 << 13) | (wloc + (2 * q) * 64 + lane);
        sbuf[p1] = (e1 << 13) | (wloc + (2 * q + 1) * 64 + lane);
    }
    __syncthreads();                                  // also publishes cps[]

    // phase D: sequential LDS read, segmented-contiguous global write
    const int bstart = b * TPB1;
#pragma unroll
    for (int k = 0; k < TPB1 / T1; ++k) {
        int j = k * T1 + tid;
        int p = sbuf[j];
        int e = (p >> 13) & 63;                       // defensive clamp
        int d = __shfl(dbase, e);                     // identical across waves
        sorted[d + j] = bstart + (p & (TPB1 - 1));
    }

    // epilogue A: this block's slice of expert_ids
    if (tid < epb) {
        int jb = b * epb + tid;
        if (jb < nb) {
            int bs2 = jb * BLK, r = 0;
            if (bs2 < total) {
                int lo = 0, hi = E;
                while (lo < hi) { int mid = (lo + hi) >> 1; if (cps[mid] <= bs2) lo = mid + 1; else hi = mid; }
                r = lo;
            }
            eids[jb] = r;
        }
    }
    // epilogue B: pad-gap fill (blocks 0..63) and tail fill (blocks 65..81)
    if (b < NE) {
        int cc = __shfl(cnts, b);                     // counts[b]
        int ob = __shfl(off_lane, b);                 // off_pad[b]
        int pe = (cc + BLK - 1) & ~(BLK - 1);
        int len = pe - cc;                            // <= 127
        if (tid < len) sorted[ob + cc + tid] = T;
    } else if (b >= E && b < E + 17) {
        int i = total + (b - E) * T1 + tid;
        if (i < M) sorted[i] = T;                     // tail <= 8255 < 17*512
    }
    if (b == 0 && tid == 0) *npp = total;
}

// ================= fallback path (R9, proven) =================
__global__ void __launch_bounds__(THREADS, 8) k_hist(const int* __restrict__ topk,
                                                     int* __restrict__ bcnt) {
    __shared__ int hist[WPB][NE];
    const int tid = threadIdx.x, w = tid >> 6, lane = tid & 63;
    hist[w][lane] = 0;
    const int base = blockIdx.x * TPB + w * 1024;
#pragma unroll
    for (int it = 0; it < 4; ++it) {
        int4 v = *(const int4*)(topk + base + it * 256 + lane * 4);
        atomicAdd(&hist[w][v.x & 63], 1);
        atomicAdd(&hist[w][v.y & 63], 1);
        atomicAdd(&hist[w][v.z & 63], 1);
        atomicAdd(&hist[w][v.w & 63], 1);
    }
    __syncthreads();
    if (tid < NE)
        bcnt[blockIdx.x * NE + tid] =
            hist[0][tid] + hist[1][tid] + hist[2][tid] + hist[3][tid];
}

__global__ void k_scan2(int* __restrict__ ctot, int* __restrict__ counts,
                        int* __restrict__ off_pad, int* __restrict__ cum_pad,
                        int* __restrict__ npp, int nc) {
    __shared__ int ct[32 * NE];
    const int tid = threadIdx.x;
    for (int i = tid; i < nc * NE; i += THREADS) ct[i] = ctot[i];
    __syncthreads();
    if (tid < NE) {
        int acc = 0;
        for (int c = 0; c < nc; ++c) { int o = ct[c * NE + tid]; ct[c * NE + tid] = acc; acc += o; }
        counts[tid] = acc;
    }
    if (tid == NE) counts[NE] = 0;
    __syncthreads();
    for (int i = tid; i < nc * NE; i += THREADS) ctot[i] = ct[i];
    if (tid == 0) {
        int run = 0;
        for (int e = 0; e < E; ++e) {
            int p = (counts[e] + BLK - 1) & ~(BLK - 1);
            off_pad[e] = run; run += p; cum_pad[e] = run;
        }
        *npp = run;
    }
}

__global__ void __launch_bounds__(THREADS) k_sort(
        const int* __restrict__ topk, const int* __restrict__ bpre,
        const int* __restrict__ ctot, const int* __restrict__ counts,
        const int* __restrict__ off_pad, const int* __restrict__ cum_pad,
        int* __restrict__ sorted, int* __restrict__ eids,
        int nb, int M, int T, int epb) {
    __shared__ int lrun[WPB][NE];
    __shared__ int wt[WPB][NE];
    __shared__ int sbuf[TPB];
    __shared__ int cps[E];
    const int tid = threadIdx.x, w = tid >> 6, lane = tid & 63;
    const int b = blockIdx.x, c = b / CHB;
    if (tid < E) cps[tid] = cum_pad[tid];
    lrun[w][lane] = 0;
    const int wstart = b * TPB + w * 1024;
    int packed[16];
#pragma unroll
    for (int it = 0; it < 16; ++it) {
        int e = topk[wstart + it * 64 + lane] & 63;
        int r = atomicAdd(&lrun[w][e], 1);
        packed[it] = (e << 10) | r;
    }
    wt[w][lane] = lrun[w][lane];
    __syncthreads();
    int woff = 0, btot = 0;
#pragma unroll
    for (int w2 = 0; w2 < WPB; ++w2) { int v = wt[w2][lane]; woff += (w2 < w) ? v : 0; btot += v; }
    int incl = btot;
#pragma unroll
    for (int d = 1; d < 64; d <<= 1) { int t = __shfl_up(incl, d); if (lane >= d) incl += t; }
    int loc = incl - btot;
    int dbase = off_pad[lane] + ctot[c * NE + lane] + bpre[b * NE + lane] - loc;
    int S = loc + woff;
    const int wloc = w * 1024;
#pragma unroll
    for (int it = 0; it < 16; ++it) {
        int e = packed[it] >> 10;
        int r = packed[it] & 1023;
        int pos = (__shfl(S, e) + r) & (TPB - 1);
        sbuf[pos] = (e << 12) | (wloc + it * 64 + lane);
    }
    __syncthreads();
    const int bstart = b * TPB;
#pragma unroll
    for (int k = 0; k < 16; ++k) {
        int j = k * THREADS + tid;
        int p = sbuf[j];
        int e = (p >> 12) & 63;
        int d = __shfl(dbase, e);
        sorted[d + j] = bstart + (p & 0xfff);
    }
    int total = cps[NE - 1];
    if (tid < epb) {
        int j = b * epb + tid;
        if (j < nb) {
            int bs2 = j * BLK, r = 0;
            if (bs2 < total) {
                int lo = 0, hi = E;
                while (lo < hi) { int mid = (lo + hi) >> 1; if (cps[mid] <= bs2) lo = mid + 1; else hi = mid; }
                r = lo;
            }
            eids[j] = r;
        }
    }
    if (b < E) {
        int cc = counts[b];
        int pe = (cc + BLK - 1) & ~(BLK - 1);
        int len = pe - cc;
        if (tid < len) sorted[off_pad[b] + cc + tid] = T;
    } else if (b < E + 33) {
        int i = total + (b - E) * THREADS + tid;
        if (i < M) sorted[i] = T;
    }
}

extern "C" void kernel_launch(void* const* d_in, const int* in_sizes, int n_in,
                              void* d_out, int out_size, void* d_ws, size_t ws_size,
                              hipStream_t stream) {
    const int* topk = (const int*)d_in[0];
    const int T = in_sizes[0];                       // 8388608
    const int M = T + E * (BLK - 1);
    const int nb = M / BLK;

    int* out = (int*)d_out;
    int* sorted = out;
    int* expert_ids = out + M;
    int* npp = out + M + nb;

    // ---- fast path: persisted-ranks, 3 launches (R13/R15 structure) ----
    bool fast = (T == NB1 * TPB1);
    size_t need = ((size_t)(T / 2) + (size_t)NB1 * NE + (size_t)NC1 * NE) * sizeof(int)
                + (size_t)NB1 * W1 * NE * sizeof(unsigned short);
    if (need > ws_size) fast = false;

    if (fast) {
        uint32_t* packed = (uint32_t*)d_ws;                          // T/2 u32
        unsigned short* wcnt16 = (unsigned short*)(packed + (size_t)T / 2);  // NB1*8*NE u16
        int* bcnt = (int*)(wcnt16 + (size_t)NB1 * W1 * NE);          // NB1*NE int
        int* ctot = bcnt + (size_t)NB1 * NE;                         // NC1*NE int
        const int epb = (nb + NB1 - 1) / NB1;                        // 65

        k_rank<<<NB1, T1, 0, stream>>>(topk, packed, wcnt16, bcnt);
        k_scan1<<<NC1, THREADS, 0, stream>>>(bcnt, ctot);
        k_sort2<<<NB1, T1, 0, stream>>>(packed, wcnt16, bcnt, ctot,
                                        sorted, expert_ids, npp, nb, M, T, epb);
        return;
    }

    // ---- fallback: proven R9 4-kernel path ----
    const int NB = T / TPB;
    const int NC = NB / CHB;
    const int epb = (nb + NB - 1) / NB;
    int* bcnt    = (int*)d_ws;
    int* ctot    = bcnt + (size_t)NB * NE;
    int* counts  = ctot + (size_t)NC * NE;
    int* off_pad = counts + E;
    int* cum_pad = off_pad + E;

    k_hist<<<NB, THREADS, 0, stream>>>(topk, bcnt);
    k_scan1<<<NC, THREADS, 0, stream>>>(bcnt, ctot);
    k_scan2<<<1, THREADS, 0, stream>>>(ctot, counts, off_pad, cum_pad, npp, NC);
    k_sort<<<NB, THREADS, 0, stream>>>(topk, bcnt, ctot, counts, off_pad, cum_pad,
                                       sorted, expert_ids, nb, M, T, epb);
}